// Round 1
// baseline (1248.764 us; speedup 1.0000x reference)
//
#include <hip/hip_runtime.h>
#include <stdint.h>

#define RES     512
#define TEXELS  (RES * RES)      // 262144
#define NPTS    1000000
#define RANK    48
#define ODIM    32

typedef unsigned int u32;

__device__ __forceinline__ float lobf(u32 u) { return __uint_as_float(u << 16); }
__device__ __forceinline__ float hibf(u32 u) { return __uint_as_float(u & 0xffff0000u); }

// round-to-nearest-even pack of two fp32 -> bf16x2 (a in low half, b in high)
__device__ __forceinline__ u32 pkbf(float a, float b) {
    u32 x = __float_as_uint(a), y = __float_as_uint(b);
    u32 xr = (x + 0x7fffu + ((x >> 16) & 1u)) >> 16;
    u32 yr = (y + 0x7fffu + ((y >> 16) & 1u)) & 0xffff0000u;
    return xr | yr;
}

// ---------------- Pass 1a: planes [48][512][512] f32 -> [texel][ch] bf16 ----
// texB = bytes per texel (128 padded-to-64ch, or 96 tight) — only 48 ch written.
__global__ __launch_bounds__(256) void transpose_planes(
    const float* __restrict__ p0, const float* __restrict__ p1,
    const float* __restrict__ p2, char* __restrict__ ws, int texB)
{
    int texel = blockIdx.x * 256 + threadIdx.x;          // grid.x = 1024
    int plane = blockIdx.y;                              // 0..2 (uniform)
    const float* src = (plane == 0) ? p0 : ((plane == 1) ? p1 : p2);
    char* dst = ws + (size_t)plane * TEXELS * texB + (size_t)texel * texB;
#pragma unroll
    for (int k = 0; k < 6; ++k) {
        uint4 q;
        q.x = pkbf(src[(size_t)(8 * k + 0) * TEXELS + texel],
                   src[(size_t)(8 * k + 1) * TEXELS + texel]);
        q.y = pkbf(src[(size_t)(8 * k + 2) * TEXELS + texel],
                   src[(size_t)(8 * k + 3) * TEXELS + texel]);
        q.z = pkbf(src[(size_t)(8 * k + 4) * TEXELS + texel],
                   src[(size_t)(8 * k + 5) * TEXELS + texel]);
        q.w = pkbf(src[(size_t)(8 * k + 6) * TEXELS + texel],
                   src[(size_t)(8 * k + 7) * TEXELS + texel]);
        *(uint4*)(dst + 16 * k) = q;
    }
}

// ---------------- Pass 1b: lines [48][512] f32 -> [pos][ch] bf16 ------------
__global__ __launch_bounds__(256) void transpose_lines(
    const float* __restrict__ lz, const float* __restrict__ ly,
    const float* __restrict__ lx, char* __restrict__ ws, int texB)
{
    int id = blockIdx.x * 256 + threadIdx.x;             // grid.x = 6 -> 1536
    int line = blockIdx.x >> 1;                          // uniform per block
    int pos = id & (RES - 1);
    const float* src = (line == 0) ? lz : ((line == 1) ? ly : lx);
    size_t plane_ws = (size_t)TEXELS * texB;
    size_t line_ws = (size_t)RES * texB;
    char* dst = ws + 3 * plane_ws + line * line_ws + (size_t)pos * texB;
#pragma unroll
    for (int k = 0; k < 6; ++k) {
        uint4 q;
        q.x = pkbf(src[(8 * k + 0) * RES + pos], src[(8 * k + 1) * RES + pos]);
        q.y = pkbf(src[(8 * k + 2) * RES + pos], src[(8 * k + 3) * RES + pos]);
        q.z = pkbf(src[(8 * k + 4) * RES + pos], src[(8 * k + 5) * RES + pos]);
        q.w = pkbf(src[(8 * k + 6) * RES + pos], src[(8 * k + 7) * RES + pos]);
        *(uint4*)(dst + 16 * k) = q;
    }
}

// ---------------- Pass 2: gather + interpolate + project --------------------
struct P2 { u32 o00, o01, o10, o11; float w00, w01, w10, w11; };

__device__ __forceinline__ P2 prep_plane(float gx, float gy, int texB) {
    float px = fminf(fmaxf((gx + 1.f) * 0.5f * 511.f, 0.f), 511.f);
    float py = fminf(fmaxf((gy + 1.f) * 0.5f * 511.f, 0.f), 511.f);
    float fx = floorf(px), fy = floorf(py);
    int x0 = (int)fx, y0 = (int)fy;
    int x1 = min(x0 + 1, RES - 1), y1 = min(y0 + 1, RES - 1);
    float wx = px - fx, wy = py - fy;
    float ix = 1.f - wx, iy = 1.f - wy;
    P2 r;
    r.o00 = (u32)(y0 * RES + x0) * (u32)texB;
    r.o01 = (u32)(y0 * RES + x1) * (u32)texB;
    r.o10 = (u32)(y1 * RES + x0) * (u32)texB;
    r.o11 = (u32)(y1 * RES + x1) * (u32)texB;
    r.w00 = iy * ix; r.w01 = iy * wx; r.w10 = wy * ix; r.w11 = wy * wx;
    return r;
}

__device__ __forceinline__ void prep_line(float g, int texB, u32& o0, u32& o1, float& w) {
    float p = fminf(fmaxf((g + 1.f) * 0.5f * 511.f, 0.f), 511.f);
    float fp = floorf(p);
    int y0 = (int)fp;
    int y1 = min(y0 + 1, RES - 1);
    w = p - fp;
    o0 = (u32)y0 * (u32)texB;
    o1 = (u32)y1 * (u32)texB;
}

#define INIT8(S, Q, W) do { \
    (S)[0] = (W) * lobf((Q).x); (S)[1] = (W) * hibf((Q).x); \
    (S)[2] = (W) * lobf((Q).y); (S)[3] = (W) * hibf((Q).y); \
    (S)[4] = (W) * lobf((Q).z); (S)[5] = (W) * hibf((Q).z); \
    (S)[6] = (W) * lobf((Q).w); (S)[7] = (W) * hibf((Q).w); } while (0)

#define ACC8(S, Q, W) do { \
    (S)[0] = fmaf((W), lobf((Q).x), (S)[0]); (S)[1] = fmaf((W), hibf((Q).x), (S)[1]); \
    (S)[2] = fmaf((W), lobf((Q).y), (S)[2]); (S)[3] = fmaf((W), hibf((Q).y), (S)[3]); \
    (S)[4] = fmaf((W), lobf((Q).z), (S)[4]); (S)[5] = fmaf((W), hibf((Q).z), (S)[5]); \
    (S)[6] = fmaf((W), lobf((Q).w), (S)[6]); (S)[7] = fmaf((W), hibf((Q).w), (S)[7]); } while (0)

__device__ __forceinline__ void accum_plane(
    const char* __restrict__ pb, const char* __restrict__ lb, P2 p,
    u32 ol0, u32 ol1, float wl, float vm[RANK])
{
    float s[RANK];
#pragma unroll
    for (int k = 0; k < 6; ++k) {
        uint4 q00 = *(const uint4*)(pb + p.o00 + 16 * k);
        uint4 q01 = *(const uint4*)(pb + p.o01 + 16 * k);
        uint4 q10 = *(const uint4*)(pb + p.o10 + 16 * k);
        uint4 q11 = *(const uint4*)(pb + p.o11 + 16 * k);
        float* sk = s + 8 * k;
        INIT8(sk, q00, p.w00);
        ACC8(sk, q01, p.w01);
        ACC8(sk, q10, p.w10);
        ACC8(sk, q11, p.w11);
    }
    float il = 1.f - wl;
#pragma unroll
    for (int k = 0; k < 6; ++k) {
        uint4 e = *(const uint4*)(lb + ol0 + 16 * k);
        uint4 f = *(const uint4*)(lb + ol1 + 16 * k);
        float* sk = s + 8 * k;
        float* vk = vm + 8 * k;
        float l;
        l = il * lobf(e.x) + wl * lobf(f.x); vk[0] = fmaf(sk[0], l, vk[0]);
        l = il * hibf(e.x) + wl * hibf(f.x); vk[1] = fmaf(sk[1], l, vk[1]);
        l = il * lobf(e.y) + wl * lobf(f.y); vk[2] = fmaf(sk[2], l, vk[2]);
        l = il * hibf(e.y) + wl * hibf(f.y); vk[3] = fmaf(sk[3], l, vk[3]);
        l = il * lobf(e.z) + wl * lobf(f.z); vk[4] = fmaf(sk[4], l, vk[4]);
        l = il * hibf(e.z) + wl * hibf(f.z); vk[5] = fmaf(sk[5], l, vk[5]);
        l = il * lobf(e.w) + wl * lobf(f.w); vk[6] = fmaf(sk[6], l, vk[6]);
        l = il * hibf(e.w) + wl * hibf(f.w); vk[7] = fmaf(sk[7], l, vk[7]);
    }
}

__global__ __launch_bounds__(256) void geo_main(
    const float* __restrict__ coords, const char* __restrict__ ws,
    const float* __restrict__ W, const float* __restrict__ Bb,
    float* __restrict__ out, int texB)
{
    int i = blockIdx.x * 256 + threadIdx.x;
    if (i >= NPTS) return;

    float gx = coords[3 * i + 0] * 2.f - 1.f;
    float gy = coords[3 * i + 1] * 2.f - 1.f;
    float gz = coords[3 * i + 2] * 2.f - 1.f;

    size_t plane_ws = (size_t)TEXELS * texB;
    size_t line_ws = (size_t)RES * texB;
    const char* pxy = ws;
    const char* pxz = ws + plane_ws;
    const char* pyz = ws + 2 * plane_ws;
    const char* lzb = ws + 3 * plane_ws;
    const char* lyb = lzb + line_ws;
    const char* lxb = lyb + line_ws;

    u32 oz0, oz1, oy0, oy1, ox0, ox1;
    float wz, wy, wx;
    prep_line(gz, texB, oz0, oz1, wz);
    prep_line(gy, texB, oy0, oy1, wy);
    prep_line(gx, texB, ox0, ox1, wx);

    float vm[RANK];
#pragma unroll
    for (int r = 0; r < RANK; ++r) vm[r] = 0.f;

    accum_plane(pxy, lzb, prep_plane(gx, gy, texB), oz0, oz1, wz, vm);
    accum_plane(pxz, lyb, prep_plane(gx, gz, texB), oy0, oy1, wy, vm);
    accum_plane(pyz, lxb, prep_plane(gy, gz, texB), ox0, ox1, wx, vm);

    // projection: out[i][o] = sum_r vm[r] * W[o][r] + Bb[o]; W is uniform -> s_loads
    float* op = out + (size_t)i * ODIM;
#pragma unroll
    for (int o = 0; o < ODIM; ++o) {
        float a = Bb[o];
#pragma unroll
        for (int r = 0; r < RANK; ++r) a = fmaf(vm[r], W[o * RANK + r], a);
        op[o] = a;
    }
}

extern "C" void kernel_launch(void* const* d_in, const int* in_sizes, int n_in,
                              void* d_out, int out_size, void* d_ws, size_t ws_size,
                              hipStream_t stream) {
    const float* coords = (const float*)d_in[0];
    const float* pxy = (const float*)d_in[1];
    const float* pxz = (const float*)d_in[2];
    const float* pyz = (const float*)d_in[3];
    const float* lz = (const float*)d_in[4];
    const float* ly = (const float*)d_in[5];
    const float* lx = (const float*)d_in[6];
    const float* W = (const float*)d_in[7];
    const float* Bb = (const float*)d_in[8];
    float* out = (float*)d_out;
    char* ws = (char*)d_ws;

    // texel stride: 64 ch padded (1 cache line) if workspace allows, else tight 48
    size_t need128 = (size_t)3 * TEXELS * 128 + (size_t)3 * RES * 128;
    int texB = (ws_size >= need128) ? 128 : 96;

    dim3 gt(TEXELS / 256, 3);
    transpose_planes<<<gt, 256, 0, stream>>>(pxy, pxz, pyz, ws, texB);
    transpose_lines<<<6, 256, 0, stream>>>(lz, ly, lx, ws, texB);

    int blocks = (NPTS + 255) / 256;
    geo_main<<<blocks, 256, 0, stream>>>(coords, ws, W, Bb, out, texB);
}

// Round 2
// 512.315 us; speedup vs baseline: 2.4375x; 2.4375x over previous
//
#include <hip/hip_runtime.h>
#include <stdint.h>

#define RES      512
#define TEXELS   (RES * RES)          // 262144
#define NPTS     1000000
#define RANK     48
#define ODIM     32
#define TEXB     96                   // 48 ch * 2B (bf16), tight
#define PLANE_WS ((size_t)TEXELS * TEXB)
#define LINE_WS  ((size_t)RES * TEXB)
#define PPB      64                   // points per block (geo_main)
#define VMS      52                   // vm LDS row stride (floats), pad 48->52

typedef unsigned int u32;

__device__ __forceinline__ float lobf(u32 u) { return __uint_as_float(u << 16); }
__device__ __forceinline__ float hibf(u32 u) { return __uint_as_float(u & 0xffff0000u); }

// RNE pack two fp32 -> bf16x2 (a low, b high)
__device__ __forceinline__ u32 pkbf(float a, float b) {
    u32 x = __float_as_uint(a), y = __float_as_uint(b);
    u32 xr = (x + 0x7fffu + ((x >> 16) & 1u)) >> 16;
    u32 yr = (y + 0x7fffu + ((y >> 16) & 1u)) & 0xffff0000u;
    return xr | yr;
}

// ---------- Pass 1a: planes [48][512][512] f32 -> [texel][48ch] bf16 --------
// 2 texels per thread, float2 coalesced reads, 16B stores.
__global__ __launch_bounds__(256) void transpose_planes(
    const float* __restrict__ p0, const float* __restrict__ p1,
    const float* __restrict__ p2, char* __restrict__ ws)
{
    int t2 = blockIdx.x * 256 + threadIdx.x;        // texel-pair, grid.x = 512
    int plane = blockIdx.y;                         // uniform
    const float* src = (plane == 0) ? p0 : ((plane == 1) ? p1 : p2);
    int tex = t2 * 2;
    u32 r0[24], r1[24];
#pragma unroll
    for (int m = 0; m < 24; ++m) {
        float2 a = *(const float2*)(src + (size_t)(2 * m) * TEXELS + tex);
        float2 b = *(const float2*)(src + (size_t)(2 * m + 1) * TEXELS + tex);
        r0[m] = pkbf(a.x, b.x);                     // texel tex,   ch 2m,2m+1
        r1[m] = pkbf(a.y, b.y);                     // texel tex+1
    }
    char* dst = ws + (size_t)plane * PLANE_WS + (size_t)tex * TEXB;
#pragma unroll
    for (int k = 0; k < 6; ++k) {
        *(uint4*)(dst + 16 * k) =
            make_uint4(r0[4 * k], r0[4 * k + 1], r0[4 * k + 2], r0[4 * k + 3]);
        *(uint4*)(dst + TEXB + 16 * k) =
            make_uint4(r1[4 * k], r1[4 * k + 1], r1[4 * k + 2], r1[4 * k + 3]);
    }
}

// ---------- Pass 1b: lines [48][512] f32 -> [pos][48ch] bf16 ----------------
__global__ __launch_bounds__(256) void transpose_lines(
    const float* __restrict__ lz, const float* __restrict__ ly,
    const float* __restrict__ lx, char* __restrict__ ws)
{
    int id = blockIdx.x * 256 + threadIdx.x;        // grid.x = 6
    int line = id >> 9;                             // uniform per block
    int pos = id & (RES - 1);
    const float* src = (line == 0) ? lz : ((line == 1) ? ly : lx);
    char* dst = ws + 3 * PLANE_WS + (size_t)line * LINE_WS + (size_t)pos * TEXB;
#pragma unroll
    for (int k = 0; k < 6; ++k) {
        uint4 q;
        q.x = pkbf(src[(8 * k + 0) * RES + pos], src[(8 * k + 1) * RES + pos]);
        q.y = pkbf(src[(8 * k + 2) * RES + pos], src[(8 * k + 3) * RES + pos]);
        q.z = pkbf(src[(8 * k + 4) * RES + pos], src[(8 * k + 5) * RES + pos]);
        q.w = pkbf(src[(8 * k + 6) * RES + pos], src[(8 * k + 7) * RES + pos]);
        *(uint4*)(dst + 16 * k) = q;
    }
}

// ---------- Pass 2: gather + interpolate (8 lanes/pt) + LDS + project -------
__device__ __forceinline__ void prep1(float g, int& i0, int& i1, float& w) {
    float p = fminf(fmaxf((g + 1.f) * 0.5f * 511.f, 0.f), 511.f);
    float fp = floorf(p);
    i0 = (int)fp;
    i1 = min(i0 + 1, RES - 1);
    w = p - fp;
}

__global__ __launch_bounds__(512, 4) void geo_main(
    const float* __restrict__ coords, const char* __restrict__ ws,
    const float* __restrict__ W, const float* __restrict__ Bb,
    float* __restrict__ out)
{
    __shared__ float vm_lds[PPB * VMS];             // 13.3 KB

    int tid = threadIdx.x;
    int ptL = tid >> 3;                             // 0..63
    int c = tid & 7;                                // chunk: ch 6c..6c+5
    int pt = blockIdx.x * PPB + ptL;                // NPTS = 15625*64 exactly

    float gx = coords[3 * pt + 0] * 2.f - 1.f;
    float gy = coords[3 * pt + 1] * 2.f - 1.f;
    float gz = coords[3 * pt + 2] * 2.f - 1.f;

    int x0, x1, y0, y1, z0, z1;
    float wx, wy, wz;
    prep1(gx, x0, x1, wx);
    prep1(gy, y0, y1, wy);
    prep1(gz, z0, z1, wz);

    const char* pxy = ws;
    const char* pxz = ws + PLANE_WS;
    const char* pyz = ws + 2 * PLANE_WS;
    const char* lzb = ws + 3 * PLANE_WS;
    const char* lyb = lzb + LINE_WS;
    const char* lxb = lyb + LINE_WS;

    u32 co = 12u * (u32)c;                          // byte offset of chunk in texel

    // --- issue all 12 corner loads + 6 line loads up front (dwordx3 each) ---
    u32 q[12][3], le[3][3], lf[3][3];
    {
        // plane xy: (gx,gy); xz: (gx,gz); yz: (gy,gz)
        u32 offs[12];
        offs[0] = (u32)(y0 * RES + x0) * TEXB + co;
        offs[1] = (u32)(y0 * RES + x1) * TEXB + co;
        offs[2] = (u32)(y1 * RES + x0) * TEXB + co;
        offs[3] = (u32)(y1 * RES + x1) * TEXB + co;
        offs[4] = (u32)(z0 * RES + x0) * TEXB + co;
        offs[5] = (u32)(z0 * RES + x1) * TEXB + co;
        offs[6] = (u32)(z1 * RES + x0) * TEXB + co;
        offs[7] = (u32)(z1 * RES + x1) * TEXB + co;
        offs[8]  = (u32)(z0 * RES + y0) * TEXB + co;
        offs[9]  = (u32)(z0 * RES + y1) * TEXB + co;
        offs[10] = (u32)(z1 * RES + y0) * TEXB + co;
        offs[11] = (u32)(z1 * RES + y1) * TEXB + co;
        const char* bases[3] = { pxy, pxz, pyz };
#pragma unroll
        for (int p = 0; p < 3; ++p) {
#pragma unroll
            for (int k = 0; k < 4; ++k) {
                const u32* s = (const u32*)(bases[p] + offs[4 * p + k]);
                q[4 * p + k][0] = s[0];
                q[4 * p + k][1] = s[1];
                q[4 * p + k][2] = s[2];
            }
        }
        const char* lb[3] = { lzb, lyb, lxb };
        u32 l0[3] = { (u32)z0 * TEXB + co, (u32)y0 * TEXB + co, (u32)x0 * TEXB + co };
        u32 l1[3] = { (u32)z1 * TEXB + co, (u32)y1 * TEXB + co, (u32)x1 * TEXB + co };
#pragma unroll
        for (int p = 0; p < 3; ++p) {
            const u32* s0 = (const u32*)(lb[p] + l0[p]);
            const u32* s1 = (const u32*)(lb[p] + l1[p]);
            le[p][0] = s0[0]; le[p][1] = s0[1]; le[p][2] = s0[2];
            lf[p][0] = s1[0]; lf[p][1] = s1[1]; lf[p][2] = s1[2];
        }
    }

    // bilinear weights per plane: xy uses (wx,wy); xz (wx,wz); yz (wy,wz)
    float pw[3][4];
    pw[0][0] = (1.f - wy) * (1.f - wx); pw[0][1] = (1.f - wy) * wx;
    pw[0][2] = wy * (1.f - wx);         pw[0][3] = wy * wx;
    pw[1][0] = (1.f - wz) * (1.f - wx); pw[1][1] = (1.f - wz) * wx;
    pw[1][2] = wz * (1.f - wx);         pw[1][3] = wz * wx;
    pw[2][0] = (1.f - wz) * (1.f - wy); pw[2][1] = (1.f - wz) * wy;
    pw[2][2] = wz * (1.f - wy);         pw[2][3] = wz * wy;
    float lw[3] = { wz, wy, wx };

    float vm[6] = { 0.f, 0.f, 0.f, 0.f, 0.f, 0.f };
#pragma unroll
    for (int p = 0; p < 3; ++p) {
        float s0 = pw[p][0], s1 = pw[p][1], s2 = pw[p][2], s3 = pw[p][3];
        float il = 1.f - lw[p], wl = lw[p];
#pragma unroll
        for (int d = 0; d < 3; ++d) {               // dword d -> ch 2d, 2d+1
            u32 a = q[4 * p + 0][d], b = q[4 * p + 1][d];
            u32 cc = q[4 * p + 2][d], dd = q[4 * p + 3][d];
            float slo = s0 * lobf(a) + s1 * lobf(b) + s2 * lobf(cc) + s3 * lobf(dd);
            float shi = s0 * hibf(a) + s1 * hibf(b) + s2 * hibf(cc) + s3 * hibf(dd);
            float llo = il * lobf(le[p][d]) + wl * lobf(lf[p][d]);
            float lhi = il * hibf(le[p][d]) + wl * hibf(lf[p][d]);
            vm[2 * d + 0] = fmaf(slo, llo, vm[2 * d + 0]);
            vm[2 * d + 1] = fmaf(shi, lhi, vm[2 * d + 1]);
        }
    }

    // stage vm -> LDS: row ptL, cols 6c..6c+5 (8-B aligned pairs)
    float* vr = vm_lds + ptL * VMS + 6 * c;
    *(float2*)(vr + 0) = make_float2(vm[0], vm[1]);
    *(float2*)(vr + 2) = make_float2(vm[2], vm[3]);
    *(float2*)(vr + 4) = make_float2(vm[4], vm[5]);

    __syncthreads();

    // --- projection: wave w owns outputs 4w..4w+3 for all 64 pts ------------
    int wav = __builtin_amdgcn_readfirstlane(tid >> 6);   // 0..7, wave-uniform
    int lane = tid & 63;                                  // local point
    int ob = wav * 4;

    const float* vmrow = vm_lds + lane * VMS;             // 208B stride, 16B aligned
    float4 bb = *(const float4*)(Bb + ob);                // uniform -> s_load
    float a0 = bb.x, a1 = bb.y, a2 = bb.z, a3 = bb.w;
#pragma unroll 4
    for (int k = 0; k < 12; ++k) {
        float4 v = *(const float4*)(vmrow + 4 * k);       // ds_read_b128
        float4 w0 = *(const float4*)(W + (ob + 0) * RANK + 4 * k);  // s_loads
        float4 w1 = *(const float4*)(W + (ob + 1) * RANK + 4 * k);
        float4 w2 = *(const float4*)(W + (ob + 2) * RANK + 4 * k);
        float4 w3 = *(const float4*)(W + (ob + 3) * RANK + 4 * k);
        a0 = fmaf(v.x, w0.x, a0); a0 = fmaf(v.y, w0.y, a0);
        a0 = fmaf(v.z, w0.z, a0); a0 = fmaf(v.w, w0.w, a0);
        a1 = fmaf(v.x, w1.x, a1); a1 = fmaf(v.y, w1.y, a1);
        a1 = fmaf(v.z, w1.z, a1); a1 = fmaf(v.w, w1.w, a1);
        a2 = fmaf(v.x, w2.x, a2); a2 = fmaf(v.y, w2.y, a2);
        a2 = fmaf(v.z, w2.z, a2); a2 = fmaf(v.w, w2.w, a2);
        a3 = fmaf(v.x, w3.x, a3); a3 = fmaf(v.y, w3.y, a3);
        a3 = fmaf(v.z, w3.z, a3); a3 = fmaf(v.w, w3.w, a3);
    }
    size_t optr = (size_t)(blockIdx.x * PPB + lane) * ODIM + ob;
    *(float4*)(out + optr) = make_float4(a0, a1, a2, a3);
}

extern "C" void kernel_launch(void* const* d_in, const int* in_sizes, int n_in,
                              void* d_out, int out_size, void* d_ws, size_t ws_size,
                              hipStream_t stream) {
    const float* coords = (const float*)d_in[0];
    const float* pxy = (const float*)d_in[1];
    const float* pxz = (const float*)d_in[2];
    const float* pyz = (const float*)d_in[3];
    const float* lz = (const float*)d_in[4];
    const float* ly = (const float*)d_in[5];
    const float* lx = (const float*)d_in[6];
    const float* W = (const float*)d_in[7];
    const float* Bb = (const float*)d_in[8];
    float* out = (float*)d_out;
    char* ws = (char*)d_ws;

    dim3 gt(TEXELS / 2 / 256, 3);
    transpose_planes<<<gt, 256, 0, stream>>>(pxy, pxz, pyz, ws);
    transpose_lines<<<6, 256, 0, stream>>>(lz, ly, lx, ws);

    geo_main<<<NPTS / PPB, 512, 0, stream>>>(coords, ws, W, Bb, out);
}

// Round 3
// 483.549 us; speedup vs baseline: 2.5825x; 1.0595x over previous
//
#include <hip/hip_runtime.h>
#include <stdint.h>

#define RES      512
#define TEXELS   (RES * RES)          // 262144
#define NPTS     1000000
#define RANK     48
#define ODIM     32
#define PPB      64                   // points per block (geo_main)
#define VMS      52                   // vm LDS row stride (floats), pad 48->52
#define TT       128                  // texels per transpose block
#define TS       25                   // LDS row stride (dwords) in transpose, coprime w/ 32

typedef unsigned int u32;

__device__ __forceinline__ float lobf(u32 u) { return __uint_as_float(u << 16); }
__device__ __forceinline__ float hibf(u32 u) { return __uint_as_float(u & 0xffff0000u); }

// RNE pack two fp32 -> bf16x2 (a low, b high)
__device__ __forceinline__ u32 pkbf(float a, float b) {
    u32 x = __float_as_uint(a), y = __float_as_uint(b);
    u32 xr = (x + 0x7fffu + ((x >> 16) & 1u)) >> 16;
    u32 yr = (y + 0x7fffu + ((y >> 16) & 1u)) & 0xffff0000u;
    return xr | yr;
}

// ---------- Pass 1a: planes [48][512][512] f32 -> [texel][ch] bf16 ----------
// LDS-tiled: coalesced channel-major reads -> LDS (stride-25 rows, conflict-
// free) -> lane-consecutive uint4 stores (full 128B lines per wave-inst).
template <int TEXB>
__global__ __launch_bounds__(256) void transpose_planes(
    const float* __restrict__ p0, const float* __restrict__ p1,
    const float* __restrict__ p2, char* __restrict__ ws)
{
    __shared__ u32 lds[TT * TS + 8];

    int t = threadIdx.x;
    int base = blockIdx.x * TT;                     // grid.x = TEXELS/TT = 2048
    int plane = blockIdx.y;                         // uniform
    const float* src = (plane == 0) ? p0 : ((plane == 1) ? p1 : p2);

    int t7 = t & (TT - 1);                          // texel within tile
    int half = t >> 7;                              // 0/1 -> dword group
#pragma unroll
    for (int j = 0; j < 12; ++j) {
        int d = half * 12 + j;                      // dword index 0..23 (ch 2d,2d+1)
        float a = src[(size_t)(2 * d) * TEXELS + base + t7];
        float b = src[(size_t)(2 * d + 1) * TEXELS + base + t7];
        lds[t7 * TS + d] = pkbf(a, b);
    }
    __syncthreads();

    char* outp = ws + (size_t)plane * TEXELS * TEXB + (size_t)base * TEXB;
    constexpr int NS = TT * TEXB / (16 * 256);      // uint4 stores per thread
#pragma unroll
    for (int s = 0; s < NS; ++s) {
        u32 o = (u32)(s * 256 + t) * 16u;           // byte offset in block region
        u32 texel, rem;
        if (TEXB == 128) { texel = o >> 7; rem = o & 127u; }
        else {                                      // TEXB == 96: o/96 = (o>>5)/3
            texel = ((o >> 5) * 43691u) >> 17;
            rem = o - texel * 96u;
        }
        u32 dw = texel * TS + (rem >> 2);
        uint4 q = make_uint4(lds[dw], lds[dw + 1], lds[dw + 2], lds[dw + 3]);
        *(uint4*)(outp + o) = q;                    // lane-consecutive, coalesced
    }
}

// ---------- Pass 1b: lines [48][512] f32 -> [pos][ch] bf16 ------------------
template <int TEXB>
__global__ __launch_bounds__(256) void transpose_lines(
    const float* __restrict__ lz, const float* __restrict__ ly,
    const float* __restrict__ lx, char* __restrict__ ws)
{
    int id = blockIdx.x * 256 + threadIdx.x;        // grid.x = 6
    int line = id >> 9;                             // uniform per block
    int pos = id & (RES - 1);
    const float* src = (line == 0) ? lz : ((line == 1) ? ly : lx);
    char* dst = ws + (size_t)3 * TEXELS * TEXB + (size_t)line * RES * TEXB
                   + (size_t)pos * TEXB;
#pragma unroll
    for (int k = 0; k < 6; ++k) {
        uint4 q;
        q.x = pkbf(src[(8 * k + 0) * RES + pos], src[(8 * k + 1) * RES + pos]);
        q.y = pkbf(src[(8 * k + 2) * RES + pos], src[(8 * k + 3) * RES + pos]);
        q.z = pkbf(src[(8 * k + 4) * RES + pos], src[(8 * k + 5) * RES + pos]);
        q.w = pkbf(src[(8 * k + 6) * RES + pos], src[(8 * k + 7) * RES + pos]);
        *(uint4*)(dst + 16 * k) = q;
    }
}

// ---------- Pass 2: gather + interpolate (8 lanes/pt) + LDS + project -------
__device__ __forceinline__ void prep1(float g, int& i0, int& i1, float& w) {
    float p = fminf(fmaxf((g + 1.f) * 0.5f * 511.f, 0.f), 511.f);
    float fp = floorf(p);
    i0 = (int)fp;
    i1 = min(i0 + 1, RES - 1);
    w = p - fp;
}

template <int TEXB>
__global__ __launch_bounds__(512, 4) void geo_main(
    const float* __restrict__ coords, const char* __restrict__ ws,
    const float* __restrict__ W, const float* __restrict__ Bb,
    float* __restrict__ out)
{
    __shared__ float vm_lds[PPB * VMS];             // 13.3 KB

    int tid = threadIdx.x;
    int ptL = tid >> 3;                             // 0..63
    int c = tid & 7;                                // chunk: ch 6c..6c+5
    int pt = blockIdx.x * PPB + ptL;                // NPTS = 15625*64 exactly

    float gx = coords[3 * pt + 0] * 2.f - 1.f;
    float gy = coords[3 * pt + 1] * 2.f - 1.f;
    float gz = coords[3 * pt + 2] * 2.f - 1.f;

    int x0, x1, y0, y1, z0, z1;
    float wx, wy, wz;
    prep1(gx, x0, x1, wx);
    prep1(gy, y0, y1, wy);
    prep1(gz, z0, z1, wz);

    const size_t PW = (size_t)TEXELS * TEXB;
    const size_t LW = (size_t)RES * TEXB;
    const char* pxy = ws;
    const char* pxz = ws + PW;
    const char* pyz = ws + 2 * PW;
    const char* lzb = ws + 3 * PW;
    const char* lyb = lzb + LW;
    const char* lxb = lyb + LW;

    u32 co = 12u * (u32)c;                          // byte offset of chunk in texel

    u32 q[12][3], le[3][3], lf[3][3];
    {
        u32 offs[12];
        offs[0] = (u32)(y0 * RES + x0) * TEXB + co;
        offs[1] = (u32)(y0 * RES + x1) * TEXB + co;
        offs[2] = (u32)(y1 * RES + x0) * TEXB + co;
        offs[3] = (u32)(y1 * RES + x1) * TEXB + co;
        offs[4] = (u32)(z0 * RES + x0) * TEXB + co;
        offs[5] = (u32)(z0 * RES + x1) * TEXB + co;
        offs[6] = (u32)(z1 * RES + x0) * TEXB + co;
        offs[7] = (u32)(z1 * RES + x1) * TEXB + co;
        offs[8]  = (u32)(z0 * RES + y0) * TEXB + co;
        offs[9]  = (u32)(z0 * RES + y1) * TEXB + co;
        offs[10] = (u32)(z1 * RES + y0) * TEXB + co;
        offs[11] = (u32)(z1 * RES + y1) * TEXB + co;
        const char* bases[3] = { pxy, pxz, pyz };
#pragma unroll
        for (int p = 0; p < 3; ++p) {
#pragma unroll
            for (int k = 0; k < 4; ++k) {
                const u32* s = (const u32*)(bases[p] + offs[4 * p + k]);
                q[4 * p + k][0] = s[0];
                q[4 * p + k][1] = s[1];
                q[4 * p + k][2] = s[2];
            }
        }
        const char* lb[3] = { lzb, lyb, lxb };
        u32 l0[3] = { (u32)z0 * TEXB + co, (u32)y0 * TEXB + co, (u32)x0 * TEXB + co };
        u32 l1[3] = { (u32)z1 * TEXB + co, (u32)y1 * TEXB + co, (u32)x1 * TEXB + co };
#pragma unroll
        for (int p = 0; p < 3; ++p) {
            const u32* s0 = (const u32*)(lb[p] + l0[p]);
            const u32* s1 = (const u32*)(lb[p] + l1[p]);
            le[p][0] = s0[0]; le[p][1] = s0[1]; le[p][2] = s0[2];
            lf[p][0] = s1[0]; lf[p][1] = s1[1]; lf[p][2] = s1[2];
        }
    }

    float pw[3][4];
    pw[0][0] = (1.f - wy) * (1.f - wx); pw[0][1] = (1.f - wy) * wx;
    pw[0][2] = wy * (1.f - wx);         pw[0][3] = wy * wx;
    pw[1][0] = (1.f - wz) * (1.f - wx); pw[1][1] = (1.f - wz) * wx;
    pw[1][2] = wz * (1.f - wx);         pw[1][3] = wz * wx;
    pw[2][0] = (1.f - wz) * (1.f - wy); pw[2][1] = (1.f - wz) * wy;
    pw[2][2] = wz * (1.f - wy);         pw[2][3] = wz * wy;
    float lw[3] = { wz, wy, wx };

    float vm[6] = { 0.f, 0.f, 0.f, 0.f, 0.f, 0.f };
#pragma unroll
    for (int p = 0; p < 3; ++p) {
        float s0 = pw[p][0], s1 = pw[p][1], s2 = pw[p][2], s3 = pw[p][3];
        float il = 1.f - lw[p], wl = lw[p];
#pragma unroll
        for (int d = 0; d < 3; ++d) {               // dword d -> ch 2d, 2d+1
            u32 a = q[4 * p + 0][d], b = q[4 * p + 1][d];
            u32 cc = q[4 * p + 2][d], dd = q[4 * p + 3][d];
            float slo = s0 * lobf(a) + s1 * lobf(b) + s2 * lobf(cc) + s3 * lobf(dd);
            float shi = s0 * hibf(a) + s1 * hibf(b) + s2 * hibf(cc) + s3 * hibf(dd);
            float llo = il * lobf(le[p][d]) + wl * lobf(lf[p][d]);
            float lhi = il * hibf(le[p][d]) + wl * hibf(lf[p][d]);
            vm[2 * d + 0] = fmaf(slo, llo, vm[2 * d + 0]);
            vm[2 * d + 1] = fmaf(shi, lhi, vm[2 * d + 1]);
        }
    }

    float* vr = vm_lds + ptL * VMS + 6 * c;
    *(float2*)(vr + 0) = make_float2(vm[0], vm[1]);
    *(float2*)(vr + 2) = make_float2(vm[2], vm[3]);
    *(float2*)(vr + 4) = make_float2(vm[4], vm[5]);

    __syncthreads();

    int wav = __builtin_amdgcn_readfirstlane(tid >> 6);   // 0..7, wave-uniform
    int lane = tid & 63;                                  // local point
    int ob = wav * 4;

    const float* vmrow = vm_lds + lane * VMS;
    float4 bb = *(const float4*)(Bb + ob);                // uniform -> s_load
    float a0 = bb.x, a1 = bb.y, a2 = bb.z, a3 = bb.w;
#pragma unroll 4
    for (int k = 0; k < 12; ++k) {
        float4 v = *(const float4*)(vmrow + 4 * k);       // ds_read_b128
        float4 w0 = *(const float4*)(W + (ob + 0) * RANK + 4 * k);  // s_loads
        float4 w1 = *(const float4*)(W + (ob + 1) * RANK + 4 * k);
        float4 w2 = *(const float4*)(W + (ob + 2) * RANK + 4 * k);
        float4 w3 = *(const float4*)(W + (ob + 3) * RANK + 4 * k);
        a0 = fmaf(v.x, w0.x, a0); a0 = fmaf(v.y, w0.y, a0);
        a0 = fmaf(v.z, w0.z, a0); a0 = fmaf(v.w, w0.w, a0);
        a1 = fmaf(v.x, w1.x, a1); a1 = fmaf(v.y, w1.y, a1);
        a1 = fmaf(v.z, w1.z, a1); a1 = fmaf(v.w, w1.w, a1);
        a2 = fmaf(v.x, w2.x, a2); a2 = fmaf(v.y, w2.y, a2);
        a2 = fmaf(v.z, w2.z, a2); a2 = fmaf(v.w, w2.w, a2);
        a3 = fmaf(v.x, w3.x, a3); a3 = fmaf(v.y, w3.y, a3);
        a3 = fmaf(v.z, w3.z, a3); a3 = fmaf(v.w, w3.w, a3);
    }
    size_t optr = (size_t)(blockIdx.x * PPB + lane) * ODIM + ob;
    *(float4*)(out + optr) = make_float4(a0, a1, a2, a3);
}

template <int TEXB>
static void launch_all(const float* coords, const float* pxy, const float* pxz,
                       const float* pyz, const float* lz, const float* ly,
                       const float* lx, const float* W, const float* Bb,
                       float* out, char* ws, hipStream_t stream) {
    dim3 gt(TEXELS / TT, 3);
    transpose_planes<TEXB><<<gt, 256, 0, stream>>>(pxy, pxz, pyz, ws);
    transpose_lines<TEXB><<<6, 256, 0, stream>>>(lz, ly, lx, ws);
    geo_main<TEXB><<<NPTS / PPB, 512, 0, stream>>>(coords, ws, W, Bb, out);
}

extern "C" void kernel_launch(void* const* d_in, const int* in_sizes, int n_in,
                              void* d_out, int out_size, void* d_ws, size_t ws_size,
                              hipStream_t stream) {
    const float* coords = (const float*)d_in[0];
    const float* pxy = (const float*)d_in[1];
    const float* pxz = (const float*)d_in[2];
    const float* pyz = (const float*)d_in[3];
    const float* lz = (const float*)d_in[4];
    const float* ly = (const float*)d_in[5];
    const float* lx = (const float*)d_in[6];
    const float* W = (const float*)d_in[7];
    const float* Bb = (const float*)d_in[8];
    float* out = (float*)d_out;
    char* ws = (char*)d_ws;

    size_t need128 = (size_t)3 * TEXELS * 128 + (size_t)3 * RES * 128;
    if (ws_size >= need128)
        launch_all<128>(coords, pxy, pxz, pyz, lz, ly, lx, W, Bb, out, ws, stream);
    else
        launch_all<96>(coords, pxy, pxz, pyz, lz, ly, lx, W, Bb, out, ws, stream);
}